// Round 8
// baseline (503.139 us; speedup 1.0000x reference)
//
#include <hip/hip_runtime.h>

#define BATCH 8
#define LT 4096
#define LV 4096
#define DIM 1024
#define TOPK 8

// ---------------------------------------------------------------------------
// Shared block-level top-8 (jax.lax.top_k semantics: descending value,
// smaller index wins ties). Deterministic -> safe to recompute per block.
// ---------------------------------------------------------------------------
__device__ __forceinline__ void block_topk(const float* __restrict__ norms, int b,
                                           float* s, float* rv, int* ri, int* tidx) {
    int tid = threadIdx.x;
    for (int i = tid; i < LT; i += 256) s[i] = norms[b * LT + i];
    __syncthreads();
    for (int r = 0; r < TOPK; ++r) {
        float bv = -2.f; int bi = 0x7fffffff;
        for (int i = tid; i < LT; i += 256) {   // ascending i -> min idx on ties
            float v = s[i];
            if (v > bv) { bv = v; bi = i; }
        }
        rv[tid] = bv; ri[tid] = bi;
        __syncthreads();
        for (int o = 128; o > 0; o >>= 1) {
            if (tid < o) {
                float v2 = rv[tid + o]; int i2 = ri[tid + o];
                if (v2 > rv[tid] || (v2 == rv[tid] && i2 < ri[tid])) {
                    rv[tid] = v2; ri[tid] = i2;
                }
            }
            __syncthreads();
        }
        if (tid == 0) { tidx[r] = ri[0]; s[ri[0]] = -1.f; }
        __syncthreads();
    }
}

// ---------------------------------------------------------------------------
// kA: squared-row-norms of text_feats + zero-fill of pad rows 8..4095 of both
// outputs, INTERLEAVED 4:1 in dispatch order so the read stream (norms) and
// write stream (fill) run concurrently instead of as two serial phases.
// 10240 blocks: blk%5<4 -> norm block (4 rows, 1/wave); blk%5==4 -> fill.
// ---------------------------------------------------------------------------
__global__ __launch_bounds__(256) void k_norm_zero(const float* __restrict__ tf,
                                                   float* __restrict__ norms,
                                                   float* __restrict__ out) {
    int blk = blockIdx.x;
    int g = blk / 5, r = blk % 5;
    if (r < 4) {
        int n = g * 4 + r;                      // 0..8191
        int wave = threadIdx.x >> 6;
        int lane = threadIdx.x & 63;
        int row  = n * 4 + wave;                // 0..32767
        const float4* p = (const float4*)(tf + (size_t)row * DIM);
        float acc = 0.f;
#pragma unroll
        for (int j = 0; j < 4; ++j) {
            float4 v = p[lane + 64 * j];
            acc += v.x * v.x + v.y * v.y + v.z * v.z + v.w * v.w;
        }
#pragma unroll
        for (int o = 32; o > 0; o >>= 1) acc += __shfl_down(acc, o, 64);
        if (lane == 0) norms[row] = acc;        // squared norm: same ordering as norm
    } else {
        int f   = g;                            // 0..2047
        int seg = f & 15;                       // 16 output segments
        int sub = f >> 4;                       // 128 fill blocks per segment
        float4* base = (float4*)out + (size_t)seg * 1048576 + 2048;
        const int len = 1046528;                // 4088*1024/4 float4s
        float4 z = make_float4(0.f, 0.f, 0.f, 0.f);
        for (int i = sub * 256 + (int)threadIdx.x; i < len; i += 128 * 256)
            base[i] = z;
    }
}

// ---------------------------------------------------------------------------
// kB: in-block top-8, then tq[b][t][d] = b_key[d] + sum_k tk[t][k] * W[d][k].
// grid (16 d-chunks of 64, 8 batches). text_keys staged in LDS; tk reads in
// the k-loop are wave-uniform (LDS broadcast). W rows L1/L2-resident.
// ---------------------------------------------------------------------------
__global__ __launch_bounds__(256) void k_tq(const float* __restrict__ tf,
                                            const float* __restrict__ norms,
                                            const float* __restrict__ W,
                                            const float* __restrict__ bias,
                                            float* __restrict__ tq) {
    __shared__ float s[LT];
    __shared__ float rv[256];
    __shared__ int   ri[256];
    __shared__ int   tidx[TOPK];
    __shared__ float tk[TOPK][DIM];
    int b = blockIdx.y, chunk = blockIdx.x, tid = threadIdx.x;
    block_topk(norms, b, s, rv, ri, tidx);
    for (int t = 0; t < TOPK; ++t) {
        const float4* src = (const float4*)(tf + ((size_t)b * LT + tidx[t]) * DIM);
        float4* dst = (float4*)tk[t];
        for (int i = tid; i < DIM / 4; i += 256) dst[i] = src[i];
    }
    __syncthreads();
    int dloc = tid & 63;
    int tp   = tid >> 6;                        // wave id: rows tp and tp+4
    int d = chunk * 64 + dloc;
    const float4* wrow = (const float4*)(W + (size_t)d * DIM);
    const float4* tk0  = (const float4*)tk[tp];
    const float4* tk1  = (const float4*)tk[tp + 4];
    float acc0 = 0.f, acc1 = 0.f;
#pragma unroll 4
    for (int k = 0; k < DIM / 4; ++k) {
        float4 w = wrow[k];
        float4 a = tk0[k], c = tk1[k];          // wave-uniform LDS broadcast
        acc0 += w.x * a.x + w.y * a.y + w.z * a.z + w.w * a.w;
        acc1 += w.x * c.x + w.y * c.y + w.z * c.z + w.w * c.w;
    }
    float bb = bias[d];
    tq[(b * TOPK + tp) * DIM + d]     = acc0 + bb;
    tq[(b * TOPK + tp + 4) * DIM + d] = acc1 + bb;
}

// ---------------------------------------------------------------------------
// kC: in-block top-8, stage visual_keys + text_keys in LDS, sim -> softmax ->
// text_out rows 0..7 and visual_out rows 0..7. One block per batch.
// ---------------------------------------------------------------------------
__global__ __launch_bounds__(256) void k_attn(const float* __restrict__ tf,
                                              const float* __restrict__ vf,
                                              const float* __restrict__ norms,
                                              const float* __restrict__ tq,
                                              float* __restrict__ out) {
    __shared__ float s[LT];
    __shared__ float rv[256];
    __shared__ int   ri[256];
    __shared__ int   tidx[TOPK];
    __shared__ float vk[TOPK][DIM];             // 32 KB
    __shared__ float tk[TOPK][DIM];             // 32 KB
    __shared__ float sim[TOPK][TOPK];
    __shared__ float he[TOPK][TOPK];
    int b = blockIdx.x, tid = threadIdx.x;
    block_topk(norms, b, s, rv, ri, tidx);
    {   // stage visual_keys = visual_feats[b, :8, :] and text_keys (gathered)
        const float4* src = (const float4*)(vf + (size_t)b * LV * DIM);
        float4* dst = (float4*)vk;
        for (int i = tid; i < TOPK * DIM / 4; i += 256) dst[i] = src[i];
        for (int t = 0; t < TOPK; ++t) {
            const float4* ts = (const float4*)(tf + ((size_t)b * LT + tidx[t]) * DIM);
            float4* td = (float4*)tk[t];
            for (int i = tid; i < DIM / 4; i += 256) td[i] = ts[i];
        }
    }
    __syncthreads();
    // sim[t][v]: 4 waves x 16 (t,v) pairs, 64-lane dot + shuffle reduce
    int wave = tid >> 6, lane = tid & 63;
    for (int p = wave * 16; p < wave * 16 + 16; ++p) {
        int t = p >> 3, v = p & 7;
        const float4* q  = (const float4*)(tq + (b * TOPK + t) * DIM);
        const float4* vv = (const float4*)vk[v];
        float acc = 0.f;
#pragma unroll
        for (int j = 0; j < 4; ++j) {
            float4 a = q[lane + 64 * j];
            float4 c = vv[lane + 64 * j];
            acc += a.x * c.x + a.y * c.y + a.z * c.z + a.w * c.w;
        }
#pragma unroll
        for (int o = 32; o > 0; o >>= 1) acc += __shfl_down(acc, o, 64);
        if (lane == 0) sim[t][v] = acc;
    }
    __syncthreads();
    if (tid < TOPK) {                           // softmax over v for row tid
        float m = -1e30f;
#pragma unroll
        for (int v = 0; v < TOPK; ++v) m = fmaxf(m, sim[tid][v]);
        float e[TOPK], ssum = 0.f;
#pragma unroll
        for (int v = 0; v < TOPK; ++v) { e[v] = expf(sim[tid][v] - m); ssum += e[v]; }
        float inv = 1.f / ssum;
#pragma unroll
        for (int v = 0; v < TOPK; ++v) he[tid][v] = e[v] * inv;
    }
    __syncthreads();
    float* to = out + (size_t)b * LT * DIM;               // text_out batch base
    float* vo = out + (size_t)(BATCH + b) * LT * DIM;     // visual_out batch base
    // text_out[t][d] = sum_v he[t][v] * vk[v][d]
    for (int i = tid; i < TOPK * DIM; i += 256) {
        int t = i >> 10, d = i & 1023;
        float acc = 0.f;
#pragma unroll
        for (int v = 0; v < TOPK; ++v) acc += he[t][v] * vk[v][d];
        to[t * DIM + d] = acc;
    }
    // visual_out[v][d] = sum_t he[t][v] * tk[t][d]   (tk now in LDS)
    for (int i = tid; i < TOPK * DIM; i += 256) {
        int v = i >> 10, d = i & 1023;
        float acc = 0.f;
#pragma unroll
        for (int t = 0; t < TOPK; ++t) acc += he[t][v] * tk[t][d];
        vo[v * DIM + d] = acc;
    }
}

extern "C" void kernel_launch(void* const* d_in, const int* in_sizes, int n_in,
                              void* d_out, int out_size, void* d_ws, size_t ws_size,
                              hipStream_t stream) {
    const float* tf   = (const float*)d_in[0];  // text_feats  (8,4096,1024)
    const float* vf   = (const float*)d_in[1];  // visual_feats(8,4096,1024)
    const float* W    = (const float*)d_in[2];  // W_key (1024,1024)
    const float* bias = (const float*)d_in[3];  // b_key (1024,)
    float* out = (float*)d_out;
    float* ws  = (float*)d_ws;
    float* norms = ws;                          // 32768 floats
    float* tq    = ws + 32768 + 64;             // 65536 floats

    k_norm_zero<<<10240, 256, 0, stream>>>(tf, norms, out);
    k_tq<<<dim3(16, 8), 256, 0, stream>>>(tf, norms, W, bias, tq);
    k_attn<<<8, 256, 0, stream>>>(tf, vf, norms, tq, out);
}